// Round 9
// baseline (1928.971 us; speedup 1.0000x reference)
//
#include <hip/hip_runtime.h>

#define RANK  32
#define DIM   128
#define BATCH 128           // rows per BLOCK-level batch (was 64 in round 5)
#define GROUPS (BATCH / 8)  // 16 global_load_lds ops per batch (8 rows / 1KB)

// Round-9: round 5 (145.7us) is the only clean+fast codegen this session:
// __launch_bounds__(256,8), 32-float pinned w2r, block-level batch. Rounds
// 6/7/8 (pipeline + waves_per_eu attempts) all died of scratch spills the
// attributes were supposed to prevent. So: keep round 5's exact register
// story and fix only its SCHEDULE: (1) BATCH 64->128 halves the number of
// drain windows and barriers per row (LDS 16KB x 8 blocks/CU = 128KB fits);
// (2) idx is prefetched one batch ahead so its ~500cy load latency drains
// under compute, not inside the serial sync->gather chain. Both changes are
// register-neutral. Everything else is byte-identical to round 5.
__global__ __launch_bounds__(256, 8) void lowrank_emb_kernel(
    const int* __restrict__ idx,
    const float* __restrict__ W1,
    const float* __restrict__ W2,
    float* __restrict__ out,
    int n_rows)
{
  __shared__ float bbuf[BATCH * RANK];  // 16KB, shared by all 4 waves

  const int lane        = threadIdx.x & 63;
  const int waveInBlock = threadIdx.x >> 6;
  const int dhalf       = waveInBlock & 1;   // which 64-dim half
  const int rhalf       = waveInBlock >> 1;  // which 64-row half
  const int dim         = dhalf * 64 + lane; // this lane's output dim

  // Per-lane W2 column (32 VGPRs), pinned (round-1 lesson: blocks remat;
  // round-4/5 lesson: 32 floats + this structure fits the 64-VGPR class).
  float w2r[RANK];
#pragma unroll
  for (int k = 0; k < RANK; ++k) w2r[k] = W2[k * DIM + dim];
#pragma unroll
  for (int k = 0; k < RANK; ++k) asm("" : "+v"(w2r[k]));

  const int rsub  = lane >> 3;  // row within an 8-row gather group
  const int chunk = lane & 7;   // 16B chunk within a row

  const int nBatches = (n_rows + BATCH - 1) / BATCH;
  const int nBlocks  = gridDim.x;
  const int lastIdx  = n_rows - 1;

  int b = blockIdx.x;
  if (b >= nBatches) return;  // block-uniform exit

  // Wave w gathers groups [4w..4w+4) = rows [32w..32w+32): it needs only its
  // own 32 indices. One coalesced 128B load into lanes 0..31 (32..63 dup).
  int ivCur;
  {
    const int r = b * BATCH + 32 * waveInBlock + (lane & 31);
    ivCur = idx[r < n_rows ? r : lastIdx];
  }

  for (; b < nBatches; b += nBlocks) {
    const int rowBase = b * BATCH;

    // (1) All waves done reading bbuf before DMA overwrites it.
    // (__syncthreads' implicit vmcnt/lgkmcnt drain retires the ds_reads.)
    __syncthreads();
    __builtin_amdgcn_sched_barrier(0);  // pin DMA issue BELOW the barrier

    // (2) Issue this batch's gathers: wave w -> 4 x 1KB DMA. Lane l fetches
    // 16B chunk (l&7) of group-row (l>>3); HW writes base+l*16 = row-major
    // [8][32] floats.
#pragma unroll
    for (int gi = 0; gi < 4; ++gi) {
      const int g = waveInBlock * 4 + gi;
      const int e = __shfl(ivCur, gi * 8 + rsub, 64);
      const float* src = W1 + (size_t)e * RANK + chunk * 4;
      __builtin_amdgcn_global_load_lds(
          (const __attribute__((address_space(1))) unsigned*)src,
          (__attribute__((address_space(3))) unsigned*)(bbuf + g * (8 * RANK)),
          16, 0, 0);
    }

    // (3) Prefetch next batch's idx; drains together with the gathers.
    {
      const int bn = b + nBlocks;
      const int r  = bn * BATCH + 32 * waveInBlock + (lane & 31);
      ivCur = idx[(bn < nBatches && r < n_rows) ? r : lastIdx];
    }

    // (4) Drain my DMAs, then make the whole batch visible to all waves.
    asm volatile("s_waitcnt vmcnt(0)" ::: "memory");
    __builtin_amdgcn_sched_barrier(0);
    __syncthreads();
    __builtin_amdgcn_sched_barrier(0);

    // (5) Compute my 64 rows x my 64-dim half: per row, 8 broadcast
    // (same-address, conflict-free) ds_read_b128 + 32 FMAs + 256B store.
    const int r0 = rhalf * 64;
    if (rowBase + BATCH <= n_rows) {
#pragma unroll 2
      for (int r = 0; r < 64; ++r) {
        const float4* rowp = reinterpret_cast<const float4*>(bbuf + (r0 + r) * RANK);
        float a0 = 0.f, a1 = 0.f;
#pragma unroll
        for (int c = 0; c < 8; ++c) {
          const float4 f = rowp[c];
          a0 = fmaf(f.x, w2r[4 * c + 0], a0);
          a1 = fmaf(f.y, w2r[4 * c + 1], a1);
          a0 = fmaf(f.z, w2r[4 * c + 2], a0);
          a1 = fmaf(f.w, w2r[4 * c + 3], a1);
        }
        out[(size_t)(rowBase + r0 + r) * DIM + dim] = a0 + a1;
      }
    } else {
      for (int r = 0; r < 64; ++r) {
        const int orow = rowBase + r0 + r;
        if (orow >= n_rows) break;
        const float4* rowp = reinterpret_cast<const float4*>(bbuf + (r0 + r) * RANK);
        float a0 = 0.f, a1 = 0.f;
#pragma unroll
        for (int c = 0; c < 8; ++c) {
          const float4 f = rowp[c];
          a0 = fmaf(f.x, w2r[4 * c + 0], a0);
          a1 = fmaf(f.y, w2r[4 * c + 1], a1);
          a0 = fmaf(f.z, w2r[4 * c + 2], a0);
          a1 = fmaf(f.w, w2r[4 * c + 3], a1);
        }
        out[(size_t)orow * DIM + dim] = a0 + a1;
      }
    }
  }
}

extern "C" void kernel_launch(void* const* d_in, const int* in_sizes, int n_in,
                              void* d_out, int out_size, void* d_ws, size_t ws_size,
                              hipStream_t stream) {
  const int*   idx = (const int*)d_in[0];   // [4096*200]
  const float* W1  = (const float*)d_in[1]; // [1e6, 32]
  const float* W2  = (const float*)d_in[2]; // [32, 128]
  float*       out = (float*)d_out;         // [4096*200, 128]
  const int n_rows = in_sizes[0];

  const int threads = 256;   // 4 waves/block
  const int blocks  = 2048;  // 8 blocks/CU resident; ~3 batches per block
  hipLaunchKernelGGL(lowrank_emb_kernel, dim3(blocks), dim3(threads), 0, stream,
                     idx, W1, W2, out, n_rows);
}

// Round 10
// 1913.686 us; speedup vs baseline: 1.0080x; 1.0080x over previous
//
#include <hip/hip_runtime.h>

#define RANK  32
#define DIM   128
#define BATCH 64            // rows per BLOCK-level batch
#define GROUPS (BATCH / 8)  // 8 global_load_lds ops (8 rows / 1KB each)

// Round-10: round 5 (145.7us) is the proven-clean codegen. Spill forensics
// across rounds 6/8/9: the asm-pinned w2r + MULTIPLE sched_barrier(0)s +
// 64-VGPR budget = allocator spills everything (pin forbids remat, barriers
// wall scheduling regions and stretch live ranges). Round 5 had exactly ONE
// sched_barrier and was clean. So: round-5 verbatim, plus the single
// cheapest schedule fix — prefetch the NEXT batch's indices during compute
// (+1 VGPR, no new fences; the next iteration's existing vmcnt(0) covers
// the load, which lands a full compute-phase early). Removes the ~500cy
// naked idx latency from every batch's serial chain.
__global__ __launch_bounds__(256, 8) void lowrank_emb_kernel(
    const int* __restrict__ idx,
    const float* __restrict__ W1,
    const float* __restrict__ W2,
    float* __restrict__ out,
    int n_rows)
{
  __shared__ float bbuf[BATCH * RANK];  // 8KB, shared by all 4 waves

  const int lane        = threadIdx.x & 63;
  const int waveInBlock = threadIdx.x >> 6;
  const int dhalf       = waveInBlock & 1;   // which 64-dim half
  const int rhalf       = waveInBlock >> 1;  // which 32-row half
  const int dim         = dhalf * 64 + lane; // this lane's output dim

  // Per-lane W2 column (32 VGPRs), pinned (round-1 lesson: blocks remat).
  float w2r[RANK];
#pragma unroll
  for (int k = 0; k < RANK; ++k) w2r[k] = W2[k * DIM + dim];
#pragma unroll
  for (int k = 0; k < RANK; ++k) asm("" : "+v"(w2r[k]));

  const int rsub  = lane >> 3;  // row within an 8-row gather group
  const int chunk = lane & 7;   // 16B chunk within a row

  const int nBatches = (n_rows + BATCH - 1) / BATCH;
  const int nBlocks  = gridDim.x;
  const int lastIdx  = n_rows - 1;

  int b = blockIdx.x;
  if (b >= nBatches) return;  // block-uniform exit

  // First batch's indices (coalesced; every wave carries all 64).
  int ivCur;
  {
    const int r = b * BATCH + lane;
    ivCur = idx[r < n_rows ? r : lastIdx];
  }

  for (; b < nBatches; b += nBlocks) {
    const int rowBase = b * BATCH;

    // (1) All waves done reading bbuf before DMA overwrites it.
    __syncthreads();

    // (2) This wave issues 2 of the block's 8 gather groups (8 rows / 1KB
    // each). Lane l fetches 16B chunk (l&7) of group-row (l>>3); HW writes
    // base + l*16, i.e. row-major [8][32] floats.
#pragma unroll
    for (int gi = 0; gi < GROUPS / 4; ++gi) {
      const int g = waveInBlock * (GROUPS / 4) + gi;
      const int e = __shfl(ivCur, g * 8 + rsub, 64);
      const float* src = W1 + (size_t)e * RANK + chunk * 4;
      __builtin_amdgcn_global_load_lds(
          (const __attribute__((address_space(1))) unsigned*)src,
          (__attribute__((address_space(3))) unsigned*)(bbuf + g * (8 * RANK)),
          16, 0, 0);
    }
    // (3) Drain MY gathers; single sched_barrier (round-5 discipline).
    asm volatile("s_waitcnt vmcnt(0)" ::: "memory");
    __builtin_amdgcn_sched_barrier(0);
    __syncthreads();  // whole 64-row batch visible to all waves

    // (4) Prefetch NEXT batch's indices now; the load's latency drains under
    // the compute below, and the next iteration's vmcnt(0) orders the use.
    {
      const int bn = b + nBlocks;
      const int r  = bn * BATCH + lane;
      ivCur = idx[(bn < nBatches && r < n_rows) ? r : lastIdx];
    }

    // (5) Compute my 32 rows x my 64-dim half: per row, 8 broadcast
    // (same-address, conflict-free) ds_read_b128 + 32 FMAs + 256B store.
    const int r0 = rhalf * 32;
    const int rowsHere = min(BATCH, n_rows - rowBase);
    if (rowsHere == BATCH) {
#pragma unroll 2
      for (int r = 0; r < 32; ++r) {
        const float4* rowp = reinterpret_cast<const float4*>(bbuf + (r0 + r) * RANK);
        float a0 = 0.f, a1 = 0.f;
#pragma unroll
        for (int c = 0; c < 8; ++c) {
          const float4 f = rowp[c];
          a0 = fmaf(f.x, w2r[4 * c + 0], a0);
          a1 = fmaf(f.y, w2r[4 * c + 1], a1);
          a0 = fmaf(f.z, w2r[4 * c + 2], a0);
          a1 = fmaf(f.w, w2r[4 * c + 3], a1);
        }
        out[(size_t)(rowBase + r0 + r) * DIM + dim] = a0 + a1;
      }
    } else {
      for (int r = 0; r < 32; ++r) {
        const int orow = rowBase + r0 + r;
        if (orow >= n_rows) break;
        const float4* rowp = reinterpret_cast<const float4*>(bbuf + (r0 + r) * RANK);
        float a0 = 0.f, a1 = 0.f;
#pragma unroll
        for (int c = 0; c < 8; ++c) {
          const float4 f = rowp[c];
          a0 = fmaf(f.x, w2r[4 * c + 0], a0);
          a1 = fmaf(f.y, w2r[4 * c + 1], a1);
          a0 = fmaf(f.z, w2r[4 * c + 2], a0);
          a1 = fmaf(f.w, w2r[4 * c + 3], a1);
        }
        out[(size_t)orow * DIM + dim] = a0 + a1;
      }
    }
  }
}

extern "C" void kernel_launch(void* const* d_in, const int* in_sizes, int n_in,
                              void* d_out, int out_size, void* d_ws, size_t ws_size,
                              hipStream_t stream) {
  const int*   idx = (const int*)d_in[0];   // [4096*200]
  const float* W1  = (const float*)d_in[1]; // [1e6, 32]
  const float* W2  = (const float*)d_in[2]; // [32, 128]
  float*       out = (float*)d_out;         // [4096*200, 128]
  const int n_rows = in_sizes[0];

  const int threads = 256;   // 4 waves/block
  const int blocks  = 2048;  // 8 blocks/CU resident; grid-stride over batches
  hipLaunchKernelGGL(lowrank_emb_kernel, dim3(blocks), dim3(threads), 0, stream,
                     idx, W1, W2, out, n_rows);
}

// Round 11
// 208.989 us; speedup vs baseline: 9.2300x; 9.1569x over previous
//
#include <hip/hip_runtime.h>

#define RANK   32
#define DIM    128
#define WBATCH 32            // rows per WAVE-private batch
#define WGROUPS (WBATCH / 8) // 4 global_load_lds ops per batch

// Round-11 = round-8 structure x round-7 allocation.
// Structure (round 8): wave-private (32-row, dim-half) tasks, private 4KB LDS
// buffer, private vmcnt drain, ZERO barriers — waves self-pace so one wave's
// ~900cy gather drain hides under the other SIMD waves' compute. Waves 2i and
// 2i+1 (same block) share a batch so the duplicate gather hits L1/L2.
// Allocation (round 7): amdgpu_waves_per_eu(4,4) — the ONLY directive that
// produced clean codegen with headroom this session (need ~66 VGPRs, cap 128;
// launch_bounds(256,8) spilled at +2 over the 64 edge in rounds 6/9/10;
// launch_bounds(256,4) shrink-and-spilled in round 4; waves_per_eu(7,7)
// spilled at 72 in round 8).
__global__ __launch_bounds__(256)
__attribute__((amdgpu_waves_per_eu(4, 4)))
void lowrank_emb_kernel(
    const int* __restrict__ idx,
    const float* __restrict__ W1,
    const float* __restrict__ W2,
    float* __restrict__ out,
    int n_rows)
{
  __shared__ float lbuf[4][WBATCH * RANK];  // 4 waves x 4KB, wave-private

  const int lane        = threadIdx.x & 63;
  const int waveInBlock = threadIdx.x >> 6;
  const int globalWave  = blockIdx.x * 4 + waveInBlock;
  const int totalWaves  = gridDim.x * 4;

  float* wbuf = lbuf[waveInBlock];

  const int nTasks  = ((n_rows + WBATCH - 1) / WBATCH) * 2;  // (batch, dhalf)
  const int lastIdx = n_rows - 1;

  // Task t: batch = t>>1, dhalf = t&1. Waves 2i/2i+1 of one block share a
  // batch; dhalf is constant across the grid-stride (totalWaves is even).
  int t = globalWave;
  if (t >= nTasks) return;

  const int dhalf = t & 1;
  const int dim   = dhalf * 64 + lane;     // this lane's output dim

  // Per-lane W2 column (32 VGPRs), pinned (round-1 lesson: blocks remat).
  float w2r[RANK];
#pragma unroll
  for (int k = 0; k < RANK; ++k) w2r[k] = W2[k * DIM + dim];
#pragma unroll
  for (int k = 0; k < RANK; ++k) asm("" : "+v"(w2r[k]));

  const int rsub  = lane >> 3;   // row within an 8-row gather group
  const int chunk = lane & 7;    // 16B chunk within a row
  const int il    = lane & 31;   // idx slot this lane carries

  // Prefetch idx for the first task.
  int ivCur;
  {
    const int r = (t >> 1) * WBATCH + il;
    ivCur = idx[r < n_rows ? r : lastIdx];
  }

  for (; t < nTasks; t += totalWaves) {
    const int rowBase = (t >> 1) * WBATCH;

    // (1) My previous task's ds_reads must retire before DMA overwrites
    // my buffer (round-3 race lesson).
    asm volatile("s_waitcnt lgkmcnt(0)" ::: "memory");
    __builtin_amdgcn_sched_barrier(0);

    // (2) Issue this batch's gathers: 4 x 1KB DMA-to-LDS. Lane l fetches 16B
    // chunk (l&7) of group-row (l>>3); HW writes base+l*16 = row-major [8][32].
#pragma unroll
    for (int g = 0; g < WGROUPS; ++g) {
      const int e = __shfl(ivCur, g * 8 + rsub, 64);
      const float* src = W1 + (size_t)e * RANK + chunk * 4;
      __builtin_amdgcn_global_load_lds(
          (const __attribute__((address_space(1))) unsigned*)src,
          (__attribute__((address_space(3))) unsigned*)(wbuf + g * (8 * RANK)),
          16, 0, 0);
    }

    // (3) Prefetch next task's idx; its latency drains with the gathers.
    {
      const int tn = t + totalWaves;
      const int r  = (tn >> 1) * WBATCH + il;
      ivCur = idx[(tn < nTasks && r < n_rows) ? r : lastIdx];
    }

    // (4) Private drain: only MY 4 DMAs (+idx load); no barrier.
    asm volatile("s_waitcnt vmcnt(0)" ::: "memory");
    __builtin_amdgcn_sched_barrier(0);

    // (5) Compute 32 rows x my 64-dim half: per row, 8 broadcast
    // (same-address, conflict-free) ds_read_b128 + 32 FMAs + 256B store.
    if (rowBase + WBATCH <= n_rows) {
#pragma unroll 2
      for (int r = 0; r < WBATCH; ++r) {
        const float4* rowp = reinterpret_cast<const float4*>(wbuf + r * RANK);
        float a0 = 0.f, a1 = 0.f;
#pragma unroll
        for (int c = 0; c < 8; ++c) {
          const float4 f = rowp[c];
          a0 = fmaf(f.x, w2r[4 * c + 0], a0);
          a1 = fmaf(f.y, w2r[4 * c + 1], a1);
          a0 = fmaf(f.z, w2r[4 * c + 2], a0);
          a1 = fmaf(f.w, w2r[4 * c + 3], a1);
        }
        out[(size_t)(rowBase + r) * DIM + dim] = a0 + a1;
      }
    } else {
      for (int r = 0; r < WBATCH; ++r) {
        const int orow = rowBase + r;
        if (orow >= n_rows) break;
        const float4* rowp = reinterpret_cast<const float4*>(wbuf + r * RANK);
        float a0 = 0.f, a1 = 0.f;
#pragma unroll
        for (int c = 0; c < 8; ++c) {
          const float4 f = rowp[c];
          a0 = fmaf(f.x, w2r[4 * c + 0], a0);
          a1 = fmaf(f.y, w2r[4 * c + 1], a1);
          a0 = fmaf(f.z, w2r[4 * c + 2], a0);
          a1 = fmaf(f.w, w2r[4 * c + 3], a1);
        }
        out[(size_t)orow * DIM + dim] = a0 + a1;
      }
    }
  }
}

extern "C" void kernel_launch(void* const* d_in, const int* in_sizes, int n_in,
                              void* d_out, int out_size, void* d_ws, size_t ws_size,
                              hipStream_t stream) {
  const int*   idx = (const int*)d_in[0];   // [4096*200]
  const float* W1  = (const float*)d_in[1]; // [1e6, 32]
  const float* W2  = (const float*)d_in[2]; // [32, 128]
  float*       out = (float*)d_out;         // [4096*200, 128]
  const int n_rows = in_sizes[0];

  const int threads = 256;   // 4 waves/block
  const int blocks  = 1024;  // 4 blocks/CU (16 waves/CU at the 128-VGPR class)
  hipLaunchKernelGGL(lowrank_emb_kernel, dim3(blocks), dim3(threads), 0, stream,
                     idx, W1, W2, out, n_rows);
}

// Round 12
// 130.419 us; speedup vs baseline: 14.7906x; 1.6024x over previous
//
#include <hip/hip_runtime.h>

#define RANK  32
#define DIM   128
#define TROWS 64   // rows per wave-task = 4 MFMA tile-rows

// Round-12: MFMA restructure. Round-11 issue-rate forensics: the broadcast
// ds_read compute structure needs 13.1M ds_read_b128 (each row read in full
// by 128 lanes) = ~130-250us of per-CU LDS-pipe time — THE wall under rounds
// 5-11. This is a GEMM (gather(W1) @ W2, K=32): one mfma_f32_16x16x32_bf16
// computes a full 16x16 out-tile. The fragment layout partitions each row
// across lanes with ZERO redundancy, so A-fragments load DIRECTLY from
// global (two float4 per lane per tile-row) — no LDS, no DMA ordering, no
// broadcast replication. W2 = 8 register-resident B-fragments (32 VGPRs,
// the proven-resident budget). bf16 inputs / f32 accumulate: worst-case
// error ~6e-5 < 1.04e-4 threshold.
// Layouts (m89/m162-verified): A[m][k],B[k][n]: lane l elem e <-> m|n=l&15,
// k=4*(l>>4)+(e&3)+16*(e>>2). C: row=(l>>4)*4+reg, col=l&15.
// Allocation: waves_per_eu(4,4) — the only proven-clean directive with
// headroom (rounds 7/11); live set ~95-110 of 128.

typedef __attribute__((ext_vector_type(8))) short bf16x8;
typedef __attribute__((ext_vector_type(4))) float f32x4;

static __device__ __forceinline__ short f2bf(float f) {
  unsigned u = __float_as_uint(f);
  return (short)((u + 0x7FFFu + ((u >> 16) & 1u)) >> 16);  // RNE
}

__global__ __launch_bounds__(256)
__attribute__((amdgpu_waves_per_eu(4, 4)))
void lowrank_emb_kernel(
    const int* __restrict__ idx,
    const float* __restrict__ W1,
    const float* __restrict__ W2,
    float* __restrict__ out,
    int n_rows)
{
  const int lane       = threadIdx.x & 63;
  const int globalWave = blockIdx.x * 4 + (threadIdx.x >> 6);
  const int totalWaves = gridDim.x * 4;

  const int q   = lane >> 4;   // k-quad selector (0..3)
  const int mn  = lane & 15;   // row-of-A / col-of-B within tile
  const int nTasks  = (n_rows + TROWS - 1) / TROWS;
  const int lastIdx = n_rows - 1;

  // B-fragments: W2 as 8 column-tiles of 16 dims, K=32. Lane l elem e holds
  // bf16(W2[4q+(e&3)+16*(e>>2)][16t+mn]). 32 VGPRs, pinned resident.
  bf16x8 bfrag[8];
#pragma unroll
  for (int t = 0; t < 8; ++t) {
    bf16x8 v;
#pragma unroll
    for (int e = 0; e < 8; ++e) {
      const int k = 4 * q + (e & 3) + 16 * (e >> 2);
      v[e] = f2bf(W2[k * DIM + 16 * t + mn]);
    }
    bfrag[t] = v;
  }
#pragma unroll
  for (int t = 0; t < 8; ++t) asm("" : "+v"(bfrag[t]));

  for (int task = globalWave; task < nTasks; task += totalWaves) {
    const int rowBase = task * TROWS;

    // Coalesced idx load: lane l carries idx[rowBase+l].
    const int r = rowBase + lane;
    const int iv = idx[r < n_rows ? r : lastIdx];

    // A gather, straight from global: tile-row tr needs row 16tr+mn, k-chunks
    // [4q,4q+4) and [16+4q,16+4q+4). All 8 loads independent and in flight
    // together; each W1 row fetched exactly once (4 lanes x 2 chunks).
    float4 alo[4], ahi[4];
#pragma unroll
    for (int tr = 0; tr < 4; ++tr) {
      const int e = __shfl(iv, tr * 16 + mn, 64);
      const float* rp = W1 + (size_t)e * RANK + 4 * q;
      alo[tr] = *reinterpret_cast<const float4*>(rp);
      ahi[tr] = *reinterpret_cast<const float4*>(rp + 16);
    }

    // Convert to A-fragments (elems 0-3: k=4q+0..3; 4-7: k=16+4q+0..3).
    bf16x8 af[4];
#pragma unroll
    for (int tr = 0; tr < 4; ++tr) {
      bf16x8 v;
      v[0] = f2bf(alo[tr].x); v[1] = f2bf(alo[tr].y);
      v[2] = f2bf(alo[tr].z); v[3] = f2bf(alo[tr].w);
      v[4] = f2bf(ahi[tr].x); v[5] = f2bf(ahi[tr].y);
      v[6] = f2bf(ahi[tr].z); v[7] = f2bf(ahi[tr].w);
      af[tr] = v;
    }

    // Compute + store, one tile-row at a time (acc regs reused: 32 live).
    const bool full = (rowBase + TROWS) <= n_rows;
#pragma unroll
    for (int tr = 0; tr < 4; ++tr) {
      f32x4 acc[8];
#pragma unroll
      for (int tc = 0; tc < 8; ++tc)
        acc[tc] = __builtin_amdgcn_mfma_f32_16x16x32_bf16(
            af[tr], bfrag[tc], (f32x4){0.f, 0.f, 0.f, 0.f}, 0, 0, 0);

      const int rb = rowBase + tr * 16 + q * 4;  // C: row=(l>>4)*4+reg
      if (full) {
#pragma unroll
        for (int rr = 0; rr < 4; ++rr) {
          float* op = out + (size_t)(rb + rr) * DIM + mn;
#pragma unroll
          for (int tc = 0; tc < 8; ++tc) op[16 * tc] = acc[tc][rr];
        }
      } else {
#pragma unroll
        for (int rr = 0; rr < 4; ++rr) {
          if (rb + rr < n_rows) {
            float* op = out + (size_t)(rb + rr) * DIM + mn;
#pragma unroll
            for (int tc = 0; tc < 8; ++tc) op[16 * tc] = acc[tc][rr];
          }
        }
      }
    }
  }
}

extern "C" void kernel_launch(void* const* d_in, const int* in_sizes, int n_in,
                              void* d_out, int out_size, void* d_ws, size_t ws_size,
                              hipStream_t stream) {
  const int*   idx = (const int*)d_in[0];   // [4096*200]
  const float* W1  = (const float*)d_in[1]; // [1e6, 32]
  const float* W2  = (const float*)d_in[2]; // [32, 128]
  float*       out = (float*)d_out;         // [4096*200, 128]
  const int n_rows = in_sizes[0];

  const int threads = 256;   // 4 waves/block
  const int blocks  = 1024;  // 4 blocks/CU resident at the 128-VGPR class
  hipLaunchKernelGGL(lowrank_emb_kernel, dim3(blocks), dim3(threads), 0, stream,
                     idx, W1, W2, out, n_rows);
}